// Round 1
// baseline (1335.793 us; speedup 1.0000x reference)
//
#include <hip/hip_runtime.h>
#include <hip/hip_bf16.h>
#include <math.h>

#define HID 1024
#define BATCH 4096
#define STEPS 12

typedef __attribute__((ext_vector_type(8))) short short8;
typedef __attribute__((ext_vector_type(4))) float f32x4;
typedef __attribute__((ext_vector_type(4))) unsigned short us4;
typedef unsigned short u16;

__device__ __forceinline__ u16 f2bf(float f) {
    union { float f; unsigned u; } v; v.f = f;
    unsigned r = v.u + 0x7fffu + ((v.u >> 16) & 1u);
    return (u16)(r >> 16);
}

__device__ __forceinline__ void gload_lds16(const u16* g, u16* l) {
    __builtin_amdgcn_global_load_lds(
        (const __attribute__((address_space(1))) unsigned*)g,
        (__attribute__((address_space(3))) unsigned*)l, 16, 0, 0);
}

// ---------------- small prep kernels ----------------

__global__ void rm_convert_bf16(const float* __restrict__ in, u16* __restrict__ out, int n4) {
    int i = blockIdx.x * 256 + threadIdx.x;
    if (i >= n4) return;
    f32x4 v = *(const f32x4*)(in + (size_t)i * 4);
    us4 o;
    o[0] = f2bf(v[0]); o[1] = f2bf(v[1]); o[2] = f2bf(v[2]); o[3] = f2bf(v[3]);
    *(us4*)(out + (size_t)i * 4) = o;
}

// in: R x C fp32 row-major -> out: C x R bf16 row-major
__global__ void rm_transpose_bf16(const float* __restrict__ in, u16* __restrict__ out, int R, int C) {
    __shared__ float t[32][33];
    int c0 = blockIdx.x * 32, r0 = blockIdx.y * 32;
    int tx = threadIdx.x & 31, ty = threadIdx.x >> 5;  // ty: 0..7
    #pragma unroll
    for (int i = 0; i < 32; i += 8)
        t[ty + i][tx] = in[(size_t)(r0 + ty + i) * C + (c0 + tx)];
    __syncthreads();
    #pragma unroll
    for (int i = 0; i < 32; i += 8)
        out[(size_t)(c0 + ty + i) * R + (r0 + tx)] = f2bf(t[tx][ty + i]);
}

// fill cs buffer: cols [0,1024)=bf16(1.0) (cos 0), cols [1024,2048)=0 (sin 0)
__global__ void rm_init_cs(u16* __restrict__ cs) {
    int i = blockIdx.x * 256 + threadIdx.x;   // over 4096*2048/4
    int col = (i * 4) & 2047;
    u16 val = (col < 1024) ? (u16)0x3F80 : (u16)0;
    us4 o; o[0] = val; o[1] = val; o[2] = val; o[3] = val;
    *(us4*)(cs + (size_t)i * 4) = o;
}

// ---------------- MFMA GEMM (m97 structure: 128x128 tile, BK=64) ----------------
// C[M=4096, N=1024] = A[M, KTOT] @ Bt^T   (Bt stored N x KTOT row-major)
// A rows come from A0 (k < KSPLIT) and A1 (k >= KSPLIT), both row-major.
// Epilogue: v = acc + bias[c] (+ prev[r][c]); EMBED: write cos/sin(v) to csOut;
//           else: Hout[r][c] = v and write cos/sin(v) to csOut.
template<int KTOT, int KSPLIT, int LDA0, int LDA1, bool EMBED>
__global__ void rm_gemm(const u16* __restrict__ A0, const u16* __restrict__ A1,
                        const u16* __restrict__ Bt,
                        const float* __restrict__ bias,
                        const float* __restrict__ prev,
                        float* __restrict__ Hout,
                        u16* __restrict__ csOut) {
    __shared__ u16 As[128 * 64];
    __shared__ u16 Bs[128 * 64];
    const int tid  = threadIdx.x;
    const int lane = tid & 63, wid = tid >> 6;
    const int tileM = blockIdx.y * 128, tileN = blockIdx.x * 128;

    const int srow = lane >> 3;          // row within a 1KB chunk (8 rows x 128B)
    const int scol = (lane & 7) * 8;     // bf16 col within BK=64

    f32x4 acc[4][4] = {};

    const int wr = wid >> 1, wc = wid & 1;
    const int lrow = lane & 15, lk8 = (lane >> 4) * 8;

    for (int kt = 0; kt < KTOT / 64; ++kt) {
        const int k0 = kt * 64;
        __syncthreads();   // previous compute done before LDS overwrite
        #pragma unroll
        for (int p = 0; p < 4; ++p) {
            const int chunk = p * 4 + wid;           // 0..15
            const int row = chunk * 8 + srow;        // 0..127
            const int kg = k0 + scol;
            const u16* g;
            if (KSPLIT >= KTOT || kg < KSPLIT)
                g = A0 + (size_t)(tileM + row) * LDA0 + kg;
            else
                g = A1 + (size_t)(tileM + row) * LDA1 + (kg - KSPLIT);
            gload_lds16(g, (u16*)((char*)As + chunk * 1024));
        }
        #pragma unroll
        for (int p = 0; p < 4; ++p) {
            const int chunk = p * 4 + wid;
            const int row = chunk * 8 + srow;        // C-column index
            const u16* g = Bt + (size_t)(tileN + row) * KTOT + k0 + scol;
            gload_lds16(g, (u16*)((char*)Bs + chunk * 1024));
        }
        __syncthreads();   // compiler drains vmcnt before barrier

        #pragma unroll
        for (int kk = 0; kk < 64; kk += 32) {
            short8 a[4], b[4];
            #pragma unroll
            for (int m = 0; m < 4; ++m)
                a[m] = *(const short8*)&As[(wr * 64 + m * 16 + lrow) * 64 + kk + lk8];
            #pragma unroll
            for (int n = 0; n < 4; ++n)
                b[n] = *(const short8*)&Bs[(wc * 64 + n * 16 + lrow) * 64 + kk + lk8];
            #pragma unroll
            for (int m = 0; m < 4; ++m)
                #pragma unroll
                for (int n = 0; n < 4; ++n)
                    acc[m][n] = __builtin_amdgcn_mfma_f32_16x16x32_bf16(a[m], b[n], acc[m][n], 0, 0, 0);
        }
    }

    // epilogue
    const int rbase = (lane >> 4) * 4;
    #pragma unroll
    for (int m = 0; m < 4; ++m) {
        #pragma unroll
        for (int n = 0; n < 4; ++n) {
            const int c = tileN + wc * 64 + n * 16 + (lane & 15);
            #pragma unroll
            for (int j = 0; j < 4; ++j) {
                const int r = tileM + wr * 64 + m * 16 + rbase + j;
                float v = acc[m][n][j] + bias[c];
                if (!EMBED && prev) v += prev[(size_t)r * HID + c];
                if (!EMBED) Hout[(size_t)r * HID + c] = v;
                float sn, cn;
                __sincosf(v, &sn, &cn);
                csOut[(size_t)r * 2048 + c] = f2bf(cn);
                csOut[(size_t)r * 2048 + HID + c] = f2bf(sn);
            }
        }
    }
}

// ---------------- final readout ----------------
// out[r] = sum_j cos(ph[r][j])*W_r[j] + sin(ph[r][j])*W_r[1024+j] + ph[r][j]*W_r[2048+j] + b_r
__global__ void rm_final(const float* __restrict__ ph, const float* __restrict__ W_r,
                         const float* __restrict__ b_r, float* __restrict__ out) {
    const int lane = threadIdx.x & 63;
    const int row  = blockIdx.x * 4 + (threadIdx.x >> 6);
    const float* p = ph + (size_t)row * HID;
    float s = 0.f;
    for (int j = lane; j < HID; j += 64) {
        float v = p[j];
        float sn, cn;
        __sincosf(v, &sn, &cn);
        s += cn * W_r[j] + sn * W_r[HID + j] + v * W_r[2 * HID + j];
    }
    #pragma unroll
    for (int off = 32; off; off >>= 1) s += __shfl_down(s, off);
    if (lane == 0) out[row] = s + b_r[0];
}

extern "C" void kernel_launch(void* const* d_in, const int* in_sizes, int n_in,
                              void* d_out, int out_size, void* d_ws, size_t ws_size,
                              hipStream_t stream) {
    const float* x   = (const float*)d_in[0];
    const float* W_e = (const float*)d_in[1];
    const float* b_e = (const float*)d_in[2];
    const float* W_d = (const float*)d_in[3];
    const float* b_d = (const float*)d_in[4];
    const float* W_r = (const float*)d_in[5];
    const float* b_r = (const float*)d_in[6];

    float* out = (float*)d_out;
    float* H   = out + BATCH;                      // 12 x 4096 x 1024 fp32

    u16* x_bf = (u16*)d_ws;                        // 4096 x 512
    u16* W_eT = x_bf + (size_t)BATCH * 512;        // 1024 x 512   (N x K)
    u16* W_dT = W_eT + (size_t)HID * 512;          // 1024 x 4096  (N x K)
    u16* xp   = W_dT + (size_t)HID * 4096;         // 4096 x 2048  (cos(p)|sin(p))
    u16* csA  = xp   + (size_t)BATCH * 2048;       // 4096 x 2048
    u16* csB  = csA  + (size_t)BATCH * 2048;

    // prep
    rm_convert_bf16<<<(BATCH * 512 / 4 + 255) / 256, 256, 0, stream>>>(x, x_bf, BATCH * 512 / 4);
    rm_transpose_bf16<<<dim3(HID / 32, 512 / 32), 256, 0, stream>>>(W_e, W_eT, 512, HID);
    rm_transpose_bf16<<<dim3(HID / 32, 4096 / 32), 256, 0, stream>>>(W_d, W_dT, 4096, HID);
    rm_init_cs<<<(BATCH * 2048 / 4) / 256, 256, 0, stream>>>(csA);

    // embed: p = x @ W_e + b_e ; xp = [cos(p) | sin(p)]
    rm_gemm<512, 512, 512, 512, true><<<dim3(HID / 128, BATCH / 128), 256, 0, stream>>>(
        x_bf, nullptr, W_eT, b_e, nullptr, nullptr, xp);

    // 12 recurrent steps
    u16* cs[2] = {csA, csB};
    for (int t = 0; t < STEPS; ++t) {
        const float* prev = (t == 0) ? nullptr : (H + (size_t)(t - 1) * BATCH * HID);
        rm_gemm<4096, 2048, 2048, 2048, false><<<dim3(HID / 128, BATCH / 128), 256, 0, stream>>>(
            cs[t & 1], xp, W_dT, b_d, prev,
            H + (size_t)t * BATCH * HID, cs[(t + 1) & 1]);
    }

    // readout from final ph = H[11]
    rm_final<<<BATCH / 4, 256, 0, stream>>>(H + (size_t)(STEPS - 1) * BATCH * HID, W_r, b_r, out);
}

// Round 2
// 425.936 us; speedup vs baseline: 3.1361x; 3.1361x over previous
//
#include <hip/hip_runtime.h>
#include <hip/hip_bf16.h>
#include <math.h>

#define HID 1024
#define BATCH 4096
#define STEPS 12

typedef __attribute__((ext_vector_type(8))) short short8;
typedef __attribute__((ext_vector_type(4))) float f32x4;
typedef __attribute__((ext_vector_type(4))) unsigned short us4;
typedef unsigned short u16;

__device__ __forceinline__ u16 f2bf(float f) {
    union { float f; unsigned u; } v; v.f = f;
    unsigned r = v.u + 0x7fffu + ((v.u >> 16) & 1u);
    return (u16)(r >> 16);
}

__device__ __forceinline__ void gload_lds16(const u16* g, u16* l) {
    __builtin_amdgcn_global_load_lds(
        (const __attribute__((address_space(1))) unsigned*)g,
        (__attribute__((address_space(3))) unsigned*)l, 16, 0, 0);
}

// ---------------- small prep kernels ----------------

__global__ void rm_convert_bf16(const float* __restrict__ in, u16* __restrict__ out, int n4) {
    int i = blockIdx.x * 256 + threadIdx.x;
    if (i >= n4) return;
    f32x4 v = *(const f32x4*)(in + (size_t)i * 4);
    us4 o;
    o[0] = f2bf(v[0]); o[1] = f2bf(v[1]); o[2] = f2bf(v[2]); o[3] = f2bf(v[3]);
    *(us4*)(out + (size_t)i * 4) = o;
}

// in: R x C fp32 row-major -> out: C x R bf16 row-major
__global__ void rm_transpose_bf16(const float* __restrict__ in, u16* __restrict__ out, int R, int C) {
    __shared__ float t[32][33];
    int c0 = blockIdx.x * 32, r0 = blockIdx.y * 32;
    int tx = threadIdx.x & 31, ty = threadIdx.x >> 5;  // ty: 0..7
    #pragma unroll
    for (int i = 0; i < 32; i += 8)
        t[ty + i][tx] = in[(size_t)(r0 + ty + i) * C + (c0 + tx)];
    __syncthreads();
    #pragma unroll
    for (int i = 0; i < 32; i += 8)
        out[(size_t)(c0 + ty + i) * R + (r0 + tx)] = f2bf(t[tx][ty + i]);
}

// w1sum[c] = sum_{k<1024} W_d[k][c]   (cos(0)=1 contribution of step 0)
__global__ void rm_w1sum(const float* __restrict__ W_d, float* __restrict__ w1sum) {
    int c  = blockIdx.x * 256 + threadIdx.x;   // gridDim.x = 4
    int k0 = blockIdx.y * 64;                  // gridDim.y = 16
    float s = 0.f;
    for (int k = 0; k < 64; ++k) s += W_d[(size_t)(k0 + k) * HID + c];
    atomicAdd(&w1sum[c], s);
}

// step 0: ph1 = base + w1sum (ph0 = 0); write H[0] and cs
__global__ void rm_step0(const float* __restrict__ base, const float* __restrict__ w1sum,
                         float* __restrict__ H0, u16* __restrict__ cs) {
    int i = blockIdx.x * 256 + threadIdx.x;    // over BATCH*HID/4
    int c4 = i & 255;
    size_t r = (size_t)(i >> 8);
    f32x4 b = *(const f32x4*)(base + (size_t)i * 4);
    f32x4 w = *(const f32x4*)(w1sum + c4 * 4);
    f32x4 v = b + w;
    *(f32x4*)(H0 + (size_t)i * 4) = v;
    us4 co, so;
    #pragma unroll
    for (int j = 0; j < 4; ++j) {
        float sn, cn; __sincosf(v[j], &sn, &cn);
        co[j] = f2bf(cn); so[j] = f2bf(sn);
    }
    *(us4*)(cs + r * 2048 + c4 * 4) = co;
    *(us4*)(cs + r * 2048 + 1024 + c4 * 4) = so;
}

// ---------------- pipelined MFMA GEMM (128x128 tile, BK=64, counted vmcnt) ----
// C[M=4096, N=1024] = A[M, KTOT] @ Bt^T   (Bt stored N-major with row stride LDB)
// MODE 0 (embed): v = acc + bias[c];            csOut <- cos|sin   (xp)
// MODE 1 (base):  v = acc + bias[c];            out32 <- v
// MODE 2 (step):  v = acc + base[r,c] + prev[r,c]; out32 <- v; csOut <- cos|sin
template<int KTOT, int LDA, int LDB, int MODE>
__global__ __launch_bounds__(256)
void rm_gemm(const u16* __restrict__ A, const u16* __restrict__ Bt,
             const float* __restrict__ bias, const float* __restrict__ base,
             const float* __restrict__ prev, float* __restrict__ out32,
             u16* __restrict__ csOut)
{
    constexpr int NT = KTOT / 64;
    __shared__ u16 sm[2][2][128 * 64];          // [buf][A/B], 64 KiB total
    const int tid = threadIdx.x, lane = tid & 63, wid = tid >> 6;

    // bijective XCD swizzle: 256 wgs, 8 XCDs -> each XCD owns 4 M-panels x all 8 N-tiles
    const int wg    = blockIdx.x;
    const int tileM = ((wg & 7) * 4 + ((wg >> 3) >> 3)) * 128;
    const int tileN = ((wg >> 3) & 7) * 128;

    const int srow = lane >> 3;                          // row within 1 KiB chunk
    const int scol = ((lane & 7) ^ srow) * 8;            // inverse-swizzled source col

    const int wr = wid >> 1, wc = wid & 1;
    const int lrow = lane & 15, lk8 = (lane >> 4) * 8;

    f32x4 acc[4][4] = {};

    auto stage = [&](int buf, int kt) {
        const int k0 = kt * 64;
        #pragma unroll
        for (int p = 0; p < 4; ++p) {
            const int chunk = p * 4 + wid;               // 0..15
            const int row = chunk * 8 + srow;            // 0..127
            gload_lds16(A  + (size_t)(tileM + row) * LDA + k0 + scol,
                        &sm[buf][0][0] + chunk * 512);
            gload_lds16(Bt + (size_t)(tileN + row) * LDB + k0 + scol,
                        &sm[buf][1][0] + chunk * 512);
        }
    };

    auto compute = [&](int buf) {
        #pragma unroll
        for (int kk = 0; kk < 64; kk += 32) {
            short8 a[4], b[4];
            #pragma unroll
            for (int m = 0; m < 4; ++m) {
                const int r = wr * 64 + m * 16 + lrow;
                a[m] = *(const short8*)&sm[buf][0][r * 64 + ((kk + lk8) ^ ((r & 7) << 3))];
            }
            #pragma unroll
            for (int n = 0; n < 4; ++n) {
                const int r = wc * 64 + n * 16 + lrow;
                b[n] = *(const short8*)&sm[buf][1][r * 64 + ((kk + lk8) ^ ((r & 7) << 3))];
            }
            #pragma unroll
            for (int m = 0; m < 4; ++m)
                #pragma unroll
                for (int n = 0; n < 4; ++n)
                    acc[m][n] = __builtin_amdgcn_mfma_f32_16x16x32_bf16(a[m], b[n], acc[m][n], 0, 0, 0);
        }
    };

    stage(0, 0);                                  // 8 loads in flight
    #pragma unroll 1
    for (int t = 0; t < NT; ++t) {
        if (t + 1 < NT) {
            stage((t + 1) & 1, t + 1);            // +8 -> 16 in flight
            asm volatile("s_waitcnt vmcnt(8)" ::: "memory");   // tile t landed (own)
        } else {
            asm volatile("s_waitcnt vmcnt(0)" ::: "memory");
        }
        __builtin_amdgcn_s_barrier();             // all waves: tile t LDS complete
        asm volatile("" ::: "memory");
        compute(t & 1);
        asm volatile("s_waitcnt lgkmcnt(0)" ::: "memory");     // my ds_reads of tile t done
        __builtin_amdgcn_s_barrier();             // safe to overwrite buf[t&1] next iter
        asm volatile("" ::: "memory");
    }

    // epilogue
    const int rbase = (lane >> 4) * 4;
    #pragma unroll
    for (int m = 0; m < 4; ++m) {
        #pragma unroll
        for (int n = 0; n < 4; ++n) {
            const int c = tileN + wc * 64 + n * 16 + (lane & 15);
            #pragma unroll
            for (int j = 0; j < 4; ++j) {
                const int r = tileM + wr * 64 + m * 16 + rbase + j;
                float v = acc[m][n][j];
                if constexpr (MODE == 2) v += base[(size_t)r * HID + c] + prev[(size_t)r * HID + c];
                else                     v += bias[c];
                if constexpr (MODE != 0) out32[(size_t)r * HID + c] = v;
                if constexpr (MODE != 1) {
                    float sn, cn;
                    __sincosf(v, &sn, &cn);
                    csOut[(size_t)r * 2048 + c]       = f2bf(cn);
                    csOut[(size_t)r * 2048 + HID + c] = f2bf(sn);
                }
            }
        }
    }
}

// ---------------- final readout ----------------
__global__ void rm_final(const float* __restrict__ ph, const float* __restrict__ W_r,
                         const float* __restrict__ b_r, float* __restrict__ out) {
    const int lane = threadIdx.x & 63;
    const int row  = blockIdx.x * 4 + (threadIdx.x >> 6);
    const float* p = ph + (size_t)row * HID;
    float s = 0.f;
    for (int j = lane; j < HID; j += 64) {
        float v = p[j];
        float sn, cn;
        __sincosf(v, &sn, &cn);
        s += cn * W_r[j] + sn * W_r[HID + j] + v * W_r[2 * HID + j];
    }
    #pragma unroll
    for (int off = 32; off; off >>= 1) s += __shfl_down(s, off);
    if (lane == 0) out[row] = s + b_r[0];
}

extern "C" void kernel_launch(void* const* d_in, const int* in_sizes, int n_in,
                              void* d_out, int out_size, void* d_ws, size_t ws_size,
                              hipStream_t stream) {
    const float* x   = (const float*)d_in[0];
    const float* W_e = (const float*)d_in[1];
    const float* b_e = (const float*)d_in[2];
    const float* W_d = (const float*)d_in[3];
    const float* b_d = (const float*)d_in[4];
    const float* W_r = (const float*)d_in[5];
    const float* b_r = (const float*)d_in[6];

    float* out = (float*)d_out;
    float* H   = out + BATCH;                      // 12 x 4096 x 1024 fp32

    u16* x_bf   = (u16*)d_ws;                      // 4096 x 512
    u16* W_eT   = x_bf + (size_t)BATCH * 512;      // 1024 x 512   (N x K)
    u16* W_dT   = W_eT + (size_t)HID * 512;        // 1024 x 4096  (N x K, full)
    u16* xp     = W_dT + (size_t)HID * 4096;       // 4096 x 2048  (cos(p)|sin(p))
    u16* csA    = xp   + (size_t)BATCH * 2048;     // 4096 x 2048
    u16* csB    = csA  + (size_t)BATCH * 2048;
    float* baseB = (float*)(csB + (size_t)BATCH * 2048);  // 4096 x 1024 fp32
    float* w1sum = baseB + (size_t)BATCH * HID;           // 1024 fp32

    // prep
    rm_convert_bf16<<<(BATCH * 512 / 4 + 255) / 256, 256, 0, stream>>>(x, x_bf, BATCH * 512 / 4);
    rm_transpose_bf16<<<dim3(HID / 32, 512 / 32), 256, 0, stream>>>(W_e, W_eT, 512, HID);
    rm_transpose_bf16<<<dim3(HID / 32, 4096 / 32), 256, 0, stream>>>(W_d, W_dT, 4096, HID);
    hipMemsetAsync(w1sum, 0, HID * sizeof(float), stream);
    rm_w1sum<<<dim3(HID / 256, 16), 256, 0, stream>>>(W_d, w1sum);

    // embed: p = x @ W_e + b_e ; xp = [cos(p) | sin(p)]
    rm_gemm<512, 512, 512, 0><<<256, 256, 0, stream>>>(
        x_bf, W_eT, b_e, nullptr, nullptr, nullptr, xp);

    // base = xp @ W_d[2048:,:] + b_d   (step-invariant half of the recurrence)
    rm_gemm<2048, 2048, 4096, 1><<<256, 256, 0, stream>>>(
        xp, W_dT + 2048, b_d, nullptr, nullptr, baseB, nullptr);

    // step 0: ph1 = base + colsum(W_d[:1024])
    rm_step0<<<BATCH * HID / 4 / 256, 256, 0, stream>>>(baseB, w1sum, H, csB);

    // steps 1..11: ph_{t+1} = ph_t + [cos|sin](ph_t) @ W_d[:2048] + base
    u16* cs[2] = {csA, csB};
    for (int t = 1; t < STEPS; ++t) {
        rm_gemm<2048, 2048, 4096, 2><<<256, 256, 0, stream>>>(
            cs[t & 1], W_dT, nullptr, baseB,
            H + (size_t)(t - 1) * BATCH * HID,
            H + (size_t)t * BATCH * HID, cs[(t + 1) & 1]);
    }

    // readout from final ph = H[11]
    rm_final<<<BATCH / 4, 256, 0, stream>>>(H + (size_t)(STEPS - 1) * BATCH * HID, W_r, b_r, out);
}